// Round 12
// baseline (194.910 us; speedup 1.0000x reference)
//
#include <hip/hip_runtime.h>

// SOM loss, MI355X — FP8 GEMM, k-permuted layout + A-frag read-ahead, triple-buffer,
// 1 barrier/K-tile. B=4096, D=1024, m=n=128, T=100.
// Xf8/Wf8 stored with within-64B-block byte permutation s = ((k>>3)&1)*32 + (k>>4)*8 + (k&7)
// so MFMA fragments are contiguous 16B chunks (ds_read_b128 at floor). Same perm on X and W
// => dot products unchanged.
// ws layout:
//   Xf8  fp8[4096][1024]         @ 0           (4 MB)
//   Wf8  fp8[16384][1024]        @ 4194304     (16 MB)
//   x2   f32[4096]               @ 20971520
//   w2   f32[16384]              @ 20987904
//   d2   bf16[4096][16384]       @ 21053440    (128 MB)
//   pmin f32[4096][128]          @ 155271168
//   pidx i32[4096][128]          @ 157368320
//   lossb f32[4096]              @ 159465472

typedef __attribute__((ext_vector_type(8))) short short8;
typedef __attribute__((ext_vector_type(16))) float f32x16;
typedef __attribute__((ext_vector_type(2))) long i64x2;
typedef unsigned short ushort_t;

#define B_ROWS 4096
#define DIM    1024
#define MN     16384
#define NJB    128

__device__ static inline ushort_t f32_to_bf16(float f) {
    unsigned u = __float_as_uint(f);
    u = (u + 0x7FFFu + ((u >> 16) & 1u)) >> 16;   // RTN-even
    return (ushort_t)u;
}
__device__ static inline float bf16_to_f32(ushort_t h) {
    return __uint_as_float(((unsigned)h) << 16);
}
__device__ static inline void gload_lds16(const void* g, void* l) {
    __builtin_amdgcn_global_load_lds(
        (const __attribute__((address_space(1))) unsigned*)g,
        (__attribute__((address_space(3))) unsigned*)l, 16, 0, 0);
}

// ---------- Kernel 1: f32 -> fp8(e4m3), k-permuted store + row sum-of-squares ----------
__global__ __launch_bounds__(256) void k_convert(
    const float* __restrict__ X, const float* __restrict__ W,
    unsigned char* __restrict__ Xf8, unsigned char* __restrict__ Wf8,
    float* __restrict__ x2, float* __restrict__ w2) {
    int row  = blockIdx.x * 4 + (threadIdx.x >> 6);
    int lane = threadIdx.x & 63;
    const float4* src;
    int* dst;
    float* sq;
    if (row < B_ROWS) {
        src = (const float4*)(X + (size_t)row * DIM);
        dst = (int*)(Xf8 + (size_t)row * DIM);
        sq  = x2 + row;
    } else {
        int r2 = row - B_ROWS;
        src = (const float4*)(W + (size_t)r2 * DIM);
        dst = (int*)(Wf8 + (size_t)r2 * DIM);
        sq  = w2 + r2;
    }
    const int t4 = lane >> 4;
    const int Foff = ((lane >> 3) & 1) * 2 + ((lane >> 1) & 3) * 4 + (lane & 1);
    float s = 0.f;
    #pragma unroll
    for (int c = 0; c < 4; ++c) {
        int F = (c * 4 + t4) * 16 + Foff;     // float4 index of permuted source
        float4 v = src[F];
        s += v.x * v.x + v.y * v.y + v.z * v.z + v.w * v.w;
        int r = __builtin_amdgcn_cvt_pk_fp8_f32(v.x, v.y, 0, false);
        r     = __builtin_amdgcn_cvt_pk_fp8_f32(v.z, v.w, r, true);
        dst[c * 64 + lane] = r;
    }
    #pragma unroll
    for (int d = 1; d < 64; d <<= 1) s += __shfl_xor(s, d);
    if (lane == 0) *sq = s;
}

// ---------- Kernel 2: 256x128-tile FP8 GEMM, A-read-ahead, 3 LDS buffers ----------
// 512 thr = 8 waves (4M x 2N), wave tile 64x64 (acc 64 f32 AGPR). K-tile 64 fp8.
// Per iter kt: issue B(kt) reads -> vmcnt(0) [staging kt+1 landed] -> BAR ->
// issue A(kt+1) reads -> lgkmcnt(4) [A-cur+B done, A-nxt in flight] ->
// STAGE(kt+2) -> MFMA(kt). One barrier per K-tile; A-frag LDS service and
// staging drain UNDER the MFMA cluster. Rotating buffers bbR/bbA/bbS (3x24KB).
__global__ __launch_bounds__(512, 3) void k_gemm(
    const unsigned char* __restrict__ Xf8, const unsigned char* __restrict__ Wf8,
    const float* __restrict__ x2, const float* __restrict__ w2,
    ushort_t* __restrict__ d2, float* __restrict__ pmin, int* __restrict__ pidx) {
    __shared__ __attribute__((aligned(1024))) unsigned char ldsb[73728];

    const int tid  = threadIdx.x;
    const int lane = tid & 63;
    const int w    = tid >> 6;
    const int wrM  = w >> 1;      // 0..3  (X-row quarter of 256)
    const int wcN  = w & 1;       // 0..1  (W-col half of 128)
    const int l31  = lane & 31;
    const int h    = lane >> 5;   // k-half

    // XCD-bijective block swizzle (2048 % 8 == 0)
    const int bid = blockIdx.x;
    const int swz = (bid & 7) * 256 + (bid >> 3);
    const int tn  = swz >> 4;     // 0..127  W-tile (128 cols)
    const int tm  = swz & 15;     // 0..15   X-tile (256 rows)

    const size_t aRow = (size_t)tm * 256;
    const size_t bRow = (size_t)tn * 128;

    // staging source precompute (inverse-swizzled), same as R11
    const unsigned char* srcA0; const unsigned char* srcA1; const unsigned char* srcB0;
    {
        int p, crow, lcol;
        p = tid * 16; crow = p >> 7; lcol = (p & 127) ^ ((crow & 7) << 4);
        srcA0 = Xf8 + (aRow + crow * 2 + (lcol >> 6)) * DIM + (lcol & 63);
        p = 8192 + tid * 16; crow = p >> 7; lcol = (p & 127) ^ ((crow & 7) << 4);
        srcA1 = Xf8 + (aRow + crow * 2 + (lcol >> 6)) * DIM + (lcol & 63);
        p = tid * 16; crow = p >> 7; lcol = (p & 127) ^ ((crow & 7) << 4);
        srcB0 = Wf8 + (bRow + crow * 2 + (lcol >> 6)) * DIM + (lcol & 63);
    }

    #define STAGE(kt, bs) do {                                                   \
        gload_lds16(srcA0 + (kt) * 64, ldsb + (bs) + tid * 16);                  \
        gload_lds16(srcA1 + (kt) * 64, ldsb + (bs) + 8192 + tid * 16);           \
        gload_lds16(srcB0 + (kt) * 64, ldsb + (bs) + 16384 + tid * 16);          \
    } while (0)

    // fragment addresses (composite-row + XOR, as R11), folded to 4 lane VGPRs
    const int rA0 = wrM * 64 + l31;
    const int rB0 = wcN * 64 + l31;
    const int fb  = (l31 & 1) * 64 + h * 32;
    const int aA0 = (rA0 >> 1) * 128 + ((fb)      ^ (((rA0 >> 1) & 7) << 4));
    const int aA1 = (rA0 >> 1) * 128 + ((fb + 16) ^ (((rA0 >> 1) & 7) << 4));
    const int aB0 = 16384 + (rB0 >> 1) * 128 + ((fb)      ^ (((rB0 >> 1) & 7) << 4));
    const int aB1 = 16384 + (rB0 >> 1) * 128 + ((fb + 16) ^ (((rB0 >> 1) & 7) << 4));

    i64x2 xc0[2], xc1[2], xn0[2], xn1[2], wq0[2], wq1[2];
    f32x16 acc[2][2];
    #pragma unroll
    for (int i = 0; i < 2; ++i)
        #pragma unroll
        for (int j = 0; j < 2; ++j) acc[i][j] = (f32x16)0.f;

    #define BAR() __builtin_amdgcn_s_barrier()
    #define SCB() __builtin_amdgcn_sched_barrier(0)
    #define RDB(bb) do {                                                          \
        wq0[0] = *(const i64x2*)(ldsb + (bb) + aB0);                              \
        wq0[1] = *(const i64x2*)(ldsb + (bb) + aB0 + 2048);                       \
        wq1[0] = *(const i64x2*)(ldsb + (bb) + aB1);                              \
        wq1[1] = *(const i64x2*)(ldsb + (bb) + aB1 + 2048);                       \
    } while (0)
    #define RDA(bb, X0, X1) do {                                                  \
        X0[0] = *(const i64x2*)(ldsb + (bb) + aA0);                               \
        X0[1] = *(const i64x2*)(ldsb + (bb) + aA0 + 2048);                        \
        X1[0] = *(const i64x2*)(ldsb + (bb) + aA1);                               \
        X1[1] = *(const i64x2*)(ldsb + (bb) + aA1 + 2048);                        \
    } while (0)
    #define MFMA16(X0, X1) do { _Pragma("unroll")                                 \
        for (int mi = 0; mi < 2; ++mi) { _Pragma("unroll")                        \
            for (int ni = 0; ni < 2; ++ni) {                                      \
                acc[mi][ni] = __builtin_amdgcn_mfma_f32_32x32x16_fp8_fp8(         \
                    wq0[ni][0], X0[mi][0], acc[mi][ni], 0, 0, 0);                 \
                acc[mi][ni] = __builtin_amdgcn_mfma_f32_32x32x16_fp8_fp8(         \
                    wq0[ni][1], X0[mi][1], acc[mi][ni], 0, 0, 0);                 \
                acc[mi][ni] = __builtin_amdgcn_mfma_f32_32x32x16_fp8_fp8(         \
                    wq1[ni][0], X1[mi][0], acc[mi][ni], 0, 0, 0);                 \
                acc[mi][ni] = __builtin_amdgcn_mfma_f32_32x32x16_fp8_fp8(         \
                    wq1[ni][1], X1[mi][1], acc[mi][ni], 0, 0, 0);                 \
            } } } while (0)

    // GB: one K-tile. DO_RDA: prefetch A(kt+1) from bbA. DO_STG: stage kt+2 -> bbS.
    #define GB(ktv, Xc0, Xc1, Xn0, Xn1, DO_RDA, DO_STG) do {                      \
        RDB(bbR);                                                                 \
        SCB();                                                                    \
        asm volatile("s_waitcnt vmcnt(0)" ::: "memory");  /* stage(kt+1) landed */\
        SCB();                                                                    \
        BAR();                                    /* visible to all waves */      \
        if (DO_RDA) { RDA(bbA, Xn0, Xn1); }                                       \
        SCB();                                                                    \
        if (DO_RDA) asm volatile("s_waitcnt lgkmcnt(4)" ::: "memory");            \
        else        asm volatile("s_waitcnt lgkmcnt(0)" ::: "memory");            \
        SCB();                                                                    \
        if (DO_STG) STAGE((ktv) + 2, bbS);                                        \
        __builtin_amdgcn_s_setprio(1);                                            \
        MFMA16(Xc0, Xc1);                                                         \
        __builtin_amdgcn_s_setprio(0);                                            \
        SCB();                                                                    \
        { int _t = bbR; bbR = bbA; bbA = bbS; bbS = _t; }                         \
    } while (0)

    // ---- prologue: T0 -> buf0, T1 -> buf1; A(0) reads issued ----
    STAGE(0, 0);
    STAGE(1, 24576);
    asm volatile("s_waitcnt vmcnt(3)" ::: "memory");   // T0 landed
    SCB();
    BAR();
    RDA(0, xc0, xc1);          // A-frags for kt=0 (4 reads in flight)
    int bbR = 0, bbA = 24576, bbS = 49152;

    for (int k2 = 0; k2 < 7; ++k2) {
        GB(2 * k2,     xc0, xc1, xn0, xn1, true, true);
        GB(2 * k2 + 1, xn0, xn1, xc0, xc1, true, true);
    }
    GB(14, xc0, xc1, xn0, xn1, true,  false);   // kt=14: prefetch A(15), no stage
    GB(15, xn0, xn1, xc0, xc1, false, false);   // kt=15: final
    BAR();   // all waves' frag reads drained before LDS reuse

    // ---- epilogue: d2 = x2 - 2*dot + w2 -> bf16, LDS-transposed coalesced store ----
    // D layout (32x32, shape-determined): col = l31 (X-row), row = (reg&3)+8*(reg>>2)
    // +4*h (W-col). per-wave 8KB: [xr:64][128B], col-byte XOR ((xr&7)<<4)
    unsigned char* wls = ldsb + w * 8192;
    const int colw = tn * 128 + wcN * 64;
    const int rowbase = tm * 256 + wrM * 64;
    float4 w2q[2][4];
    #pragma unroll
    for (int ni = 0; ni < 2; ++ni)
        #pragma unroll
        for (int q = 0; q < 4; ++q)
            w2q[ni][q] = *(const float4*)(w2 + colw + ni * 32 + q * 8 + h * 4);

    float mnA[2]; int ixA[2];
    #pragma unroll
    for (int mi = 0; mi < 2; ++mi) {
        const int xr = mi * 32 + l31;
        const float xx = x2[rowbase + xr];
        float mn = __builtin_inff(); int ix = 0x7fffffff;
        #pragma unroll
        for (int ni = 0; ni < 2; ++ni) {
            #pragma unroll
            for (int q = 0; q < 4; ++q) {
                float dv[4];
                ushort4 st;
                #pragma unroll
                for (int t = 0; t < 4; ++t) {
                    dv[t] = xx - 2.f * acc[mi][ni][q * 4 + t] + w2q[ni][q][t];
                    st[t] = (unsigned short)f32_to_bf16(dv[t]);
                }
                *(ushort4*)(wls + xr * 128
                            + ((ni * 64 + q * 16 + h * 8) ^ ((xr & 7) << 4))) = st;
                #pragma unroll
                for (int t = 0; t < 4; ++t) {
                    const int cand = colw + ni * 32 + q * 8 + h * 4 + t;
                    if (dv[t] < mn || (dv[t] == mn && cand < ix)) { mn = dv[t]; ix = cand; }
                }
            }
        }
        float om = __shfl_xor(mn, 32);
        int   oi = __shfl_xor(ix, 32);
        if (om < mn || (om == mn && oi < ix)) { mn = om; ix = oi; }
        mnA[mi] = mn; ixA[mi] = ix;
    }
    asm volatile("s_waitcnt lgkmcnt(0)" ::: "memory");  // wave-private LDS writes done
    SCB();
    // read back transposed: 8 lanes x 16B = 128B contiguous per d2 row
    #pragma unroll
    for (int j = 0; j < 8; ++j) {
        const int rl = j * 8 + (lane >> 3);      // row_local 0..63
        const int cb = (lane & 7) * 16;
        short8 v = *(const short8*)(wls + rl * 128 + (cb ^ ((rl & 7) << 4)));
        *(short8*)((char*)(d2 + (size_t)(rowbase + rl) * MN + colw) + cb) = v;
    }
    __syncthreads();
    // per-row argmin partials across the 2 N-waves
    float* smin = (float*)ldsb;            // [256][2]
    int*   sidx = (int*)(ldsb + 2048);     // [256][2]
    if (lane < 32) {
        #pragma unroll
        for (int mi = 0; mi < 2; ++mi) {
            const int rloc = wrM * 64 + mi * 32 + l31;
            smin[rloc * 2 + wcN] = mnA[mi];
            sidx[rloc * 2 + wcN] = ixA[mi];
        }
    }
    __syncthreads();
    if (tid < 256) {
        float m0 = smin[tid * 2];     int i0 = sidx[tid * 2];
        float m1 = smin[tid * 2 + 1]; int i1 = sidx[tid * 2 + 1];
        bool take1 = (m1 < m0) || (m1 == m0 && i1 < i0);
        const int row = tm * 256 + tid;
        pmin[(size_t)row * NJB + tn] = take1 ? m1 : m0;
        pidx[(size_t)row * NJB + tn] = take1 ? i1 : i0;
    }
    #undef STAGE
    #undef BAR
    #undef SCB
    #undef RDB
    #undef RDA
    #undef MFMA16
    #undef GB
}

// ---------- Kernel 3: fused argmin-finish + influence-weighted row sum ----------
__global__ __launch_bounds__(256) void k_loss(
    const ushort_t* __restrict__ d2, const float* __restrict__ pmin,
    const int* __restrict__ pidx, float* __restrict__ lossb) {
    __shared__ float etab[255];
    __shared__ float red[4];
    __shared__ int bmu_s;
    int t = threadIdx.x;
    if (t < 255) etab[t] = __expf(-(float)(t * t) * 1e-4f);  // exp(-r^2/T^2), T=100
    int row = blockIdx.x;
    if (t < 64) {
        float m0 = pmin[(size_t)row * NJB + t];
        int   i0 = pidx[(size_t)row * NJB + t];
        float m1 = pmin[(size_t)row * NJB + t + 64];
        int   i1 = pidx[(size_t)row * NJB + t + 64];
        if (m1 < m0 || (m1 == m0 && i1 < i0)) { m0 = m1; i0 = i1; }
        #pragma unroll
        for (int d = 1; d < 64; d <<= 1) {
            float om = __shfl_xor(m0, d);
            int   oi = __shfl_xor(i0, d);
            if (om < m0 || (om == m0 && oi < i0)) { m0 = om; i0 = oi; }
        }
        if (t == 0) bmu_s = i0;
    }
    __syncthreads();
    int bl = bmu_s;
    int bi = bl >> 7, bj = bl & 127;
    const ushort_t* dr = d2 + (size_t)row * MN;
    float s = 0.f;
    #pragma unroll
    for (int c = 0; c < 8; ++c) {
        int j = c * 2048 + t * 8;
        short8 v = *(const short8*)&dr[j];
        int di = abs((j >> 7) - bi);
        int jc = j & 127;
        #pragma unroll
        for (int u = 0; u < 8; ++u) {
            int mh = di + abs(jc + u - bj);
            s += bf16_to_f32((ushort_t)v[u]) * etab[mh];
        }
    }
    #pragma unroll
    for (int d = 1; d < 64; d <<= 1) s += __shfl_xor(s, d);
    if ((t & 63) == 0) red[t >> 6] = s;
    __syncthreads();
    if (t == 0) lossb[row] = red[0] + red[1] + red[2] + red[3];
}

// ---------- Kernel 4: final deterministic reduce ----------
__global__ __launch_bounds__(256) void k_final(
    const float* __restrict__ lossb, float* __restrict__ out) {
    __shared__ float red[4];
    int t = threadIdx.x;
    float s = 0.f;
    #pragma unroll
    for (int k = 0; k < 16; ++k) s += lossb[t + k * 256];
    #pragma unroll
    for (int d = 1; d < 64; d <<= 1) s += __shfl_xor(s, d);
    if ((t & 63) == 0) red[t >> 6] = s;
    __syncthreads();
    if (t == 0) out[0] = (red[0] + red[1] + red[2] + red[3]) * (1.0f / 128.0f);
}

extern "C" void kernel_launch(void* const* d_in, const int* in_sizes, int n_in,
                              void* d_out, int out_size, void* d_ws, size_t ws_size,
                              hipStream_t stream) {
    const float* X = (const float*)d_in[0];
    const float* W = (const float*)d_in[1];
    unsigned char* ws = (unsigned char*)d_ws;
    unsigned char* Xf8 = ws;
    unsigned char* Wf8 = ws + 4194304;
    float*    x2   = (float*)(ws + 20971520);
    float*    w2   = (float*)(ws + 20987904);
    ushort_t* d2   = (ushort_t*)(ws + 21053440);
    float*    pmin = (float*)(ws + 155271168);
    int*      pidx = (int*)(ws + 157368320);
    float*    lossb= (float*)(ws + 159465472);

    k_convert<<<5120, 256, 0, stream>>>(X, W, Xf8, Wf8, x2, w2);
    k_gemm<<<2048, 512, 0, stream>>>(Xf8, Wf8, x2, w2, d2, pmin, pidx);
    k_loss<<<4096, 256, 0, stream>>>(d2, pmin, pidx, lossb);
    k_final<<<1, 256, 0, stream>>>(lossb, (float*)d_out);
}

// Round 13
// 170.123 us; speedup vs baseline: 1.1457x; 1.1457x over previous
//
#include <hip/hip_runtime.h>

// SOM loss, MI355X — FP8 GEMM, k-permuted layout, 128x128 tile / 4-wave blocks
// (4 co-resident blocks per CU for cross-block overlap). B=4096, D=1024, m=n=128, T=100.
// Xf8/Wf8 stored with within-64B-block byte permutation s = ((k>>3)&1)*32 + (k>>4)*8 + (k&7)
// so MFMA fragments are contiguous 16B chunks (ds_read_b128 at floor). Same perm on X and W
// => dot products unchanged.
// ws layout:
//   Xf8  fp8[4096][1024]         @ 0           (4 MB)
//   Wf8  fp8[16384][1024]        @ 4194304     (16 MB)
//   x2   f32[4096]               @ 20971520
//   w2   f32[16384]              @ 20987904
//   d2   bf16[4096][16384]       @ 21053440    (128 MB)
//   pmin f32[4096][128]          @ 155271168
//   pidx i32[4096][128]          @ 157368320
//   lossb f32[4096]              @ 159465472

typedef __attribute__((ext_vector_type(8))) short short8;
typedef __attribute__((ext_vector_type(16))) float f32x16;
typedef __attribute__((ext_vector_type(2))) long i64x2;
typedef unsigned short ushort_t;

#define B_ROWS 4096
#define DIM    1024
#define MN     16384
#define NJB    128

__device__ static inline ushort_t f32_to_bf16(float f) {
    unsigned u = __float_as_uint(f);
    u = (u + 0x7FFFu + ((u >> 16) & 1u)) >> 16;   // RTN-even
    return (ushort_t)u;
}
__device__ static inline float bf16_to_f32(ushort_t h) {
    return __uint_as_float(((unsigned)h) << 16);
}
__device__ static inline void gload_lds16(const void* g, void* l) {
    __builtin_amdgcn_global_load_lds(
        (const __attribute__((address_space(1))) unsigned*)g,
        (__attribute__((address_space(3))) unsigned*)l, 16, 0, 0);
}

// ---------- Kernel 1: f32 -> fp8(e4m3), k-permuted store + row sum-of-squares ----------
__global__ __launch_bounds__(256) void k_convert(
    const float* __restrict__ X, const float* __restrict__ W,
    unsigned char* __restrict__ Xf8, unsigned char* __restrict__ Wf8,
    float* __restrict__ x2, float* __restrict__ w2) {
    int row  = blockIdx.x * 4 + (threadIdx.x >> 6);
    int lane = threadIdx.x & 63;
    const float4* src;
    int* dst;
    float* sq;
    if (row < B_ROWS) {
        src = (const float4*)(X + (size_t)row * DIM);
        dst = (int*)(Xf8 + (size_t)row * DIM);
        sq  = x2 + row;
    } else {
        int r2 = row - B_ROWS;
        src = (const float4*)(W + (size_t)r2 * DIM);
        dst = (int*)(Wf8 + (size_t)r2 * DIM);
        sq  = w2 + r2;
    }
    const int t4 = lane >> 4;
    const int Foff = ((lane >> 3) & 1) * 2 + ((lane >> 1) & 3) * 4 + (lane & 1);
    float s = 0.f;
    #pragma unroll
    for (int c = 0; c < 4; ++c) {
        int F = (c * 4 + t4) * 16 + Foff;     // float4 index of permuted source
        float4 v = src[F];
        s += v.x * v.x + v.y * v.y + v.z * v.z + v.w * v.w;
        int r = __builtin_amdgcn_cvt_pk_fp8_f32(v.x, v.y, 0, false);
        r     = __builtin_amdgcn_cvt_pk_fp8_f32(v.z, v.w, r, true);
        dst[c * 64 + lane] = r;
    }
    #pragma unroll
    for (int d = 1; d < 64; d <<= 1) s += __shfl_xor(s, d);
    if (lane == 0) *sq = s;
}

// ---------- Kernel 2: 128x128-tile FP8 GEMM (v_mfma_f32_32x32x16_fp8_fp8) ----------
// 256 thr = 4 waves (2M x 2N), wave tile 64x64 (acc 64 f32 AGPR). K-tile 64 fp8.
// LDS: 2 dbuf x 16KB (A 128x64B + B 128x64B), composite 128B rows, XOR ((crow&7)<<4).
// 16 K-tiles, 2-barrier dbuf loop (R11 structure verbatim, per-wave). 4 blocks/CU
// co-resident (32KB LDS, 128 regs/wave) -> cross-block MFMA/LDS overlap.
__global__ __launch_bounds__(256, 4) void k_gemm(
    const unsigned char* __restrict__ Xf8, const unsigned char* __restrict__ Wf8,
    const float* __restrict__ x2, const float* __restrict__ w2,
    ushort_t* __restrict__ d2, float* __restrict__ pmin, int* __restrict__ pidx) {
    __shared__ __attribute__((aligned(1024))) unsigned char ldsb[32768];

    const int tid  = threadIdx.x;
    const int lane = tid & 63;
    const int w    = tid >> 6;    // 0..3
    const int wrM  = w >> 1;      // 0..1  (X-row half of 128)
    const int wcN  = w & 1;       // 0..1  (W-col half of 128)
    const int l31  = lane & 31;
    const int h    = lane >> 5;   // k-half

    // XCD-bijective block swizzle (4096 % 8 == 0)
    const int bid = blockIdx.x;
    const int swz = (bid & 7) * 512 + (bid >> 3);
    const int tn  = swz >> 5;     // 0..127  W-tile (128 cols)
    const int tm  = swz & 31;     // 0..31   X-tile (128 rows)

    const size_t aRow = (size_t)tm * 128;
    const size_t bRow = (size_t)tn * 128;

    // staging source precompute (inverse-swizzled). Each thread: 2 A chunks + 2 B
    // chunks of 16B. Chunk at region offset p: crow = p>>7, lcol = (p&127)^((crow&7)<<4),
    // logical row = 2crow + (lcol>>6), k-byte = lcol&63. p and p+4096: same lcol,
    // row += 64 -> +65536 bytes in global.
    const unsigned char* srcA0; const unsigned char* srcB0;
    {
        int p = tid * 16;
        int crow = p >> 7, lcol = (p & 127) ^ ((crow & 7) << 4);
        srcA0 = Xf8 + (aRow + crow * 2 + (lcol >> 6)) * DIM + (lcol & 63);
        srcB0 = Wf8 + (bRow + crow * 2 + (lcol >> 6)) * DIM + (lcol & 63);
    }
    const unsigned char* srcA1 = srcA0 + 65536;   // row+64, same in-row offset
    const unsigned char* srcB1 = srcB0 + 65536;

    #define STAGE(kt, bs) do {                                                   \
        gload_lds16(srcA0 + (kt) * 64, ldsb + (bs) + tid * 16);                  \
        gload_lds16(srcA1 + (kt) * 64, ldsb + (bs) + 4096 + tid * 16);           \
        gload_lds16(srcB0 + (kt) * 64, ldsb + (bs) + 8192 + tid * 16);           \
        gload_lds16(srcB1 + (kt) * 64, ldsb + (bs) + 12288 + tid * 16);          \
    } while (0)

    // fragment addresses (composite-row + XOR): A region [0,8KB), B [8KB,16KB)
    const int rA0 = wrM * 64 + l31;
    const int rB0 = wcN * 64 + l31;
    const int fb  = (l31 & 1) * 64 + h * 32;
    const int aA0 = (rA0 >> 1) * 128 + ((fb)      ^ (((rA0 >> 1) & 7) << 4));
    const int aA1 = (rA0 >> 1) * 128 + ((fb + 16) ^ (((rA0 >> 1) & 7) << 4));
    const int aB0 = 8192 + (rB0 >> 1) * 128 + ((fb)      ^ (((rB0 >> 1) & 7) << 4));
    const int aB1 = 8192 + (rB0 >> 1) * 128 + ((fb + 16) ^ (((rB0 >> 1) & 7) << 4));

    f32x16 acc[2][2];
    #pragma unroll
    for (int i = 0; i < 2; ++i)
        #pragma unroll
        for (int j = 0; j < 2; ++j) acc[i][j] = (f32x16)0.f;

    #define BAR() __builtin_amdgcn_s_barrier()
    #define SCB() __builtin_amdgcn_sched_barrier(0)

    // prologue: T0 -> buf0, T1 -> buf1
    STAGE(0, 0);
    STAGE(1, 16384);
    asm volatile("s_waitcnt vmcnt(4)" ::: "memory");   // T0 landed
    SCB();
    BAR();

    for (int kt = 0; kt < 16; ++kt) {
        const int bb = (kt & 1) * 16384;
        i64x2 xq0[2], xq1[2], wq0[2], wq1[2];
        #pragma unroll
        for (int mi = 0; mi < 2; ++mi) {
            xq0[mi] = *(const i64x2*)(ldsb + bb + aA0 + mi * 2048);
            xq1[mi] = *(const i64x2*)(ldsb + bb + aA1 + mi * 2048);
        }
        #pragma unroll
        for (int ni = 0; ni < 2; ++ni) {
            wq0[ni] = *(const i64x2*)(ldsb + bb + aB0 + ni * 2048);
            wq1[ni] = *(const i64x2*)(ldsb + bb + aB1 + ni * 2048);
        }
        asm volatile("s_waitcnt lgkmcnt(4)" ::: "memory");
        SCB();
        __builtin_amdgcn_s_setprio(1);
        #pragma unroll
        for (int mi = 0; mi < 2; ++mi)
            #pragma unroll
            for (int ni = 0; ni < 2; ++ni) {
                acc[mi][ni] = __builtin_amdgcn_mfma_f32_32x32x16_fp8_fp8(
                    wq0[ni][0], xq0[mi][0], acc[mi][ni], 0, 0, 0);   // ks0
                acc[mi][ni] = __builtin_amdgcn_mfma_f32_32x32x16_fp8_fp8(
                    wq0[ni][1], xq0[mi][1], acc[mi][ni], 0, 0, 0);   // ks1
            }
        __builtin_amdgcn_s_setprio(0);
        asm volatile("s_waitcnt lgkmcnt(0)" ::: "memory");
        SCB();
        __builtin_amdgcn_s_setprio(1);
        #pragma unroll
        for (int mi = 0; mi < 2; ++mi)
            #pragma unroll
            for (int ni = 0; ni < 2; ++ni) {
                acc[mi][ni] = __builtin_amdgcn_mfma_f32_32x32x16_fp8_fp8(
                    wq1[ni][0], xq1[mi][0], acc[mi][ni], 0, 0, 0);   // ks2
                acc[mi][ni] = __builtin_amdgcn_mfma_f32_32x32x16_fp8_fp8(
                    wq1[ni][1], xq1[mi][1], acc[mi][ni], 0, 0, 0);   // ks3
            }
        __builtin_amdgcn_s_setprio(0);
        SCB();
        BAR();                                 // all waves' reads of bb drained
        if (kt < 14) {
            STAGE(kt + 2, kt & 1 ? 16384 : 0);
            asm volatile("s_waitcnt vmcnt(4)" ::: "memory");  // kt+1 landed
            SCB();
            BAR();
        } else if (kt == 14) {
            asm volatile("s_waitcnt vmcnt(0)" ::: "memory");  // kt=15 landed
            SCB();
            BAR();
        }
    }

    // ---- epilogue: d2 = x2 - 2*dot + w2 -> bf16, LDS-transposed coalesced store ----
    // D layout (32x32, shape-determined): col = l31 (X-row), row = (reg&3)+8*(reg>>2)
    // +4*h (W-col). per-wave 8KB: [xr:64][128B], col-byte XOR ((xr&7)<<4)
    unsigned char* wls = ldsb + w * 8192;
    const int colw = tn * 128 + wcN * 64;
    const int rowbase = tm * 128 + wrM * 64;
    float4 w2q[2][4];
    #pragma unroll
    for (int ni = 0; ni < 2; ++ni)
        #pragma unroll
        for (int q = 0; q < 4; ++q)
            w2q[ni][q] = *(const float4*)(w2 + colw + ni * 32 + q * 8 + h * 4);

    float mnA[2]; int ixA[2];
    #pragma unroll
    for (int mi = 0; mi < 2; ++mi) {
        const int xr = mi * 32 + l31;
        const float xx = x2[rowbase + xr];
        float mn = __builtin_inff(); int ix = 0x7fffffff;
        #pragma unroll
        for (int ni = 0; ni < 2; ++ni) {
            #pragma unroll
            for (int q = 0; q < 4; ++q) {
                float dv[4];
                ushort4 st;
                #pragma unroll
                for (int t = 0; t < 4; ++t) {
                    dv[t] = xx - 2.f * acc[mi][ni][q * 4 + t] + w2q[ni][q][t];
                    st[t] = (unsigned short)f32_to_bf16(dv[t]);
                }
                *(ushort4*)(wls + xr * 128
                            + ((ni * 64 + q * 16 + h * 8) ^ ((xr & 7) << 4))) = st;
                #pragma unroll
                for (int t = 0; t < 4; ++t) {
                    const int cand = colw + ni * 32 + q * 8 + h * 4 + t;
                    if (dv[t] < mn || (dv[t] == mn && cand < ix)) { mn = dv[t]; ix = cand; }
                }
            }
        }
        float om = __shfl_xor(mn, 32);
        int   oi = __shfl_xor(ix, 32);
        if (om < mn || (om == mn && oi < ix)) { mn = om; ix = oi; }
        mnA[mi] = mn; ixA[mi] = ix;
    }
    asm volatile("s_waitcnt lgkmcnt(0)" ::: "memory");  // wave-private LDS writes done
    SCB();
    // read back transposed: 8 lanes x 16B = 128B contiguous per d2 row
    #pragma unroll
    for (int j = 0; j < 8; ++j) {
        const int rl = j * 8 + (lane >> 3);      // row_local 0..63
        const int cb = (lane & 7) * 16;
        short8 v = *(const short8*)(wls + rl * 128 + (cb ^ ((rl & 7) << 4)));
        *(short8*)((char*)(d2 + (size_t)(rowbase + rl) * MN + colw) + cb) = v;
    }
    __syncthreads();
    // per-row argmin partials across the 2 N-waves
    float* smin = (float*)ldsb;            // [128][2]
    int*   sidx = (int*)(ldsb + 1024);     // [128][2]
    if (lane < 32) {
        #pragma unroll
        for (int mi = 0; mi < 2; ++mi) {
            const int rloc = wrM * 64 + mi * 32 + l31;
            smin[rloc * 2 + wcN] = mnA[mi];
            sidx[rloc * 2 + wcN] = ixA[mi];
        }
    }
    __syncthreads();
    if (tid < 128) {
        float m0 = smin[tid * 2];     int i0 = sidx[tid * 2];
        float m1 = smin[tid * 2 + 1]; int i1 = sidx[tid * 2 + 1];
        bool take1 = (m1 < m0) || (m1 == m0 && i1 < i0);
        const int row = tm * 128 + tid;
        pmin[(size_t)row * NJB + tn] = take1 ? m1 : m0;
        pidx[(size_t)row * NJB + tn] = take1 ? i1 : i0;
    }
    #undef STAGE
    #undef BAR
    #undef SCB
}

// ---------- Kernel 3: fused argmin-finish + influence-weighted row sum ----------
__global__ __launch_bounds__(256) void k_loss(
    const ushort_t* __restrict__ d2, const float* __restrict__ pmin,
    const int* __restrict__ pidx, float* __restrict__ lossb) {
    __shared__ float etab[255];
    __shared__ float red[4];
    __shared__ int bmu_s;
    int t = threadIdx.x;
    if (t < 255) etab[t] = __expf(-(float)(t * t) * 1e-4f);  // exp(-r^2/T^2), T=100
    int row = blockIdx.x;
    if (t < 64) {
        float m0 = pmin[(size_t)row * NJB + t];
        int   i0 = pidx[(size_t)row * NJB + t];
        float m1 = pmin[(size_t)row * NJB + t + 64];
        int   i1 = pidx[(size_t)row * NJB + t + 64];
        if (m1 < m0 || (m1 == m0 && i1 < i0)) { m0 = m1; i0 = i1; }
        #pragma unroll
        for (int d = 1; d < 64; d <<= 1) {
            float om = __shfl_xor(m0, d);
            int   oi = __shfl_xor(i0, d);
            if (om < m0 || (om == m0 && oi < i0)) { m0 = om; i0 = oi; }
        }
        if (t == 0) bmu_s = i0;
    }
    __syncthreads();
    int bl = bmu_s;
    int bi = bl >> 7, bj = bl & 127;
    const ushort_t* dr = d2 + (size_t)row * MN;
    float s = 0.f;
    #pragma unroll
    for (int c = 0; c < 8; ++c) {
        int j = c * 2048 + t * 8;
        short8 v = *(const short8*)&dr[j];
        int di = abs((j >> 7) - bi);
        int jc = j & 127;
        #pragma unroll
        for (int u = 0; u < 8; ++u) {
            int mh = di + abs(jc + u - bj);
            s += bf16_to_f32((ushort_t)v[u]) * etab[mh];
        }
    }
    #pragma unroll
    for (int d = 1; d < 64; d <<= 1) s += __shfl_xor(s, d);
    if ((t & 63) == 0) red[t >> 6] = s;
    __syncthreads();
    if (t == 0) lossb[row] = red[0] + red[1] + red[2] + red[3];
}

// ---------- Kernel 4: final deterministic reduce ----------
__global__ __launch_bounds__(256) void k_final(
    const float* __restrict__ lossb, float* __restrict__ out) {
    __shared__ float red[4];
    int t = threadIdx.x;
    float s = 0.f;
    #pragma unroll
    for (int k = 0; k < 16; ++k) s += lossb[t + k * 256];
    #pragma unroll
    for (int d = 1; d < 64; d <<= 1) s += __shfl_xor(s, d);
    if ((t & 63) == 0) red[t >> 6] = s;
    __syncthreads();
    if (t == 0) out[0] = (red[0] + red[1] + red[2] + red[3]) * (1.0f / 128.0f);
}

extern "C" void kernel_launch(void* const* d_in, const int* in_sizes, int n_in,
                              void* d_out, int out_size, void* d_ws, size_t ws_size,
                              hipStream_t stream) {
    const float* X = (const float*)d_in[0];
    const float* W = (const float*)d_in[1];
    unsigned char* ws = (unsigned char*)d_ws;
    unsigned char* Xf8 = ws;
    unsigned char* Wf8 = ws + 4194304;
    float*    x2   = (float*)(ws + 20971520);
    float*    w2   = (float*)(ws + 20987904);
    ushort_t* d2   = (ushort_t*)(ws + 21053440);
    float*    pmin = (float*)(ws + 155271168);
    int*      pidx = (int*)(ws + 157368320);
    float*    lossb= (float*)(ws + 159465472);

    k_convert<<<5120, 256, 0, stream>>>(X, W, Xf8, Wf8, x2, w2);
    k_gemm<<<4096, 256, 0, stream>>>(Xf8, Wf8, x2, w2, d2, pmin, pidx);
    k_loss<<<4096, 256, 0, stream>>>(d2, pmin, pidx, lossb);
    k_final<<<1, 256, 0, stream>>>(lossb, (float*)d_out);
}

// Round 14
// 161.574 us; speedup vs baseline: 1.2063x; 1.0529x over previous
//
#include <hip/hip_runtime.h>

// SOM loss, MI355X — FP8 GEMM, k-permuted layout + per-block K-tile rotation
// (de-phases co-resident blocks so LDS bursts overlap other blocks' MFMA).
// B=4096, D=1024, m=n=128, T=100.
// Xf8/Wf8 stored with within-64B-block byte permutation s = ((k>>3)&1)*32 + (k>>4)*8 + (k&7)
// so MFMA fragments are contiguous 16B chunks (ds_read_b128 at floor). Same perm on X and W
// => dot products unchanged.
// ws layout:
//   Xf8  fp8[4096][1024]         @ 0           (4 MB)
//   Wf8  fp8[16384][1024]        @ 4194304     (16 MB)
//   x2   f32[4096]               @ 20971520
//   w2   f32[16384]              @ 20987904
//   d2   bf16[4096][16384]       @ 21053440    (128 MB)
//   pmin f32[4096][128]          @ 155271168
//   pidx i32[4096][128]          @ 157368320
//   lossb f32[4096]              @ 159465472

typedef __attribute__((ext_vector_type(8))) short short8;
typedef __attribute__((ext_vector_type(16))) float f32x16;
typedef __attribute__((ext_vector_type(2))) long i64x2;
typedef unsigned short ushort_t;

#define B_ROWS 4096
#define DIM    1024
#define MN     16384
#define NJB    128

__device__ static inline ushort_t f32_to_bf16(float f) {
    unsigned u = __float_as_uint(f);
    u = (u + 0x7FFFu + ((u >> 16) & 1u)) >> 16;   // RTN-even
    return (ushort_t)u;
}
__device__ static inline float bf16_to_f32(ushort_t h) {
    return __uint_as_float(((unsigned)h) << 16);
}
__device__ static inline void gload_lds16(const void* g, void* l) {
    __builtin_amdgcn_global_load_lds(
        (const __attribute__((address_space(1))) unsigned*)g,
        (__attribute__((address_space(3))) unsigned*)l, 16, 0, 0);
}

// ---------- Kernel 1: f32 -> fp8(e4m3), k-permuted store + row sum-of-squares ----------
__global__ __launch_bounds__(256) void k_convert(
    const float* __restrict__ X, const float* __restrict__ W,
    unsigned char* __restrict__ Xf8, unsigned char* __restrict__ Wf8,
    float* __restrict__ x2, float* __restrict__ w2) {
    int row  = blockIdx.x * 4 + (threadIdx.x >> 6);
    int lane = threadIdx.x & 63;
    const float4* src;
    int* dst;
    float* sq;
    if (row < B_ROWS) {
        src = (const float4*)(X + (size_t)row * DIM);
        dst = (int*)(Xf8 + (size_t)row * DIM);
        sq  = x2 + row;
    } else {
        int r2 = row - B_ROWS;
        src = (const float4*)(W + (size_t)r2 * DIM);
        dst = (int*)(Wf8 + (size_t)r2 * DIM);
        sq  = w2 + r2;
    }
    const int t4 = lane >> 4;
    const int Foff = ((lane >> 3) & 1) * 2 + ((lane >> 1) & 3) * 4 + (lane & 1);
    float s = 0.f;
    #pragma unroll
    for (int c = 0; c < 4; ++c) {
        int F = (c * 4 + t4) * 16 + Foff;     // float4 index of permuted source
        float4 v = src[F];
        s += v.x * v.x + v.y * v.y + v.z * v.z + v.w * v.w;
        int r = __builtin_amdgcn_cvt_pk_fp8_f32(v.x, v.y, 0, false);
        r     = __builtin_amdgcn_cvt_pk_fp8_f32(v.z, v.w, r, true);
        dst[c * 64 + lane] = r;
    }
    #pragma unroll
    for (int d = 1; d < 64; d <<= 1) s += __shfl_xor(s, d);
    if (lane == 0) *sq = s;
}

// ---------- Kernel 2: 256x128-tile FP8 GEMM (v_mfma_f32_32x32x16_fp8_fp8) ----------
// 512 thr = 8 waves (4M x 2N), wave tile 64x64 (acc 64 f32 AGPR). K-tile 64 fp8.
// LDS: 2 dbuf x 24KB, composite 128B rows, XOR ((crow&7)<<4). 16 K-tiles,
// 2-barrier dbuf loop. PER-BLOCK K-ROTATION: kt_eff = (kt + phase) & 15,
// phase = (bid&7)*2 — co-resident blocks hit LDS-burst/MFMA phases at different
// times, so one block's frag reads drain under another's MFMA (anti-convoy).
// Summation order over kt changes only f32 rounding (tolerance >> that).
__global__ __launch_bounds__(512, 3) void k_gemm(
    const unsigned char* __restrict__ Xf8, const unsigned char* __restrict__ Wf8,
    const float* __restrict__ x2, const float* __restrict__ w2,
    ushort_t* __restrict__ d2, float* __restrict__ pmin, int* __restrict__ pidx) {
    __shared__ __attribute__((aligned(1024))) unsigned char ldsb[65536];

    const int tid  = threadIdx.x;
    const int lane = tid & 63;
    const int w    = tid >> 6;
    const int wrM  = w >> 1;      // 0..3  (X-row quarter of 256)
    const int wcN  = w & 1;       // 0..1  (W-col half of 128)
    const int l31  = lane & 31;
    const int h    = lane >> 5;   // k-half

    // XCD-bijective block swizzle (2048 % 8 == 0)
    const int bid = blockIdx.x;
    const int swz = (bid & 7) * 256 + (bid >> 3);
    const int tn  = swz >> 4;     // 0..127  W-tile (128 cols)
    const int tm  = swz & 15;     // 0..15   X-tile (256 rows)
    const int phase = (bid & 7) * 2;   // K-rotation phase

    const size_t aRow = (size_t)tm * 256;
    const size_t bRow = (size_t)tn * 128;

    // staging source precompute (inverse-swizzled)
    const unsigned char* srcA0; const unsigned char* srcA1; const unsigned char* srcB0;
    {
        int p, crow, lcol;
        p = tid * 16; crow = p >> 7; lcol = (p & 127) ^ ((crow & 7) << 4);
        srcA0 = Xf8 + (aRow + crow * 2 + (lcol >> 6)) * DIM + (lcol & 63);
        p = 8192 + tid * 16; crow = p >> 7; lcol = (p & 127) ^ ((crow & 7) << 4);
        srcA1 = Xf8 + (aRow + crow * 2 + (lcol >> 6)) * DIM + (lcol & 63);
        p = tid * 16; crow = p >> 7; lcol = (p & 127) ^ ((crow & 7) << 4);
        srcB0 = Wf8 + (bRow + crow * 2 + (lcol >> 6)) * DIM + (lcol & 63);
    }

    #define STAGE(kt, buf) do {                                                  \
        const int _kt = (kt) & 15;                                               \
        gload_lds16(srcA0 + _kt * 64, ldsb + (buf) * 24576 + tid * 16);          \
        gload_lds16(srcA1 + _kt * 64, ldsb + (buf) * 24576 + 8192 + tid * 16);   \
        gload_lds16(srcB0 + _kt * 64, ldsb + (buf) * 24576 + 16384 + tid * 16);  \
    } while (0)

    // fragment addressing: row r = base + l31; composite crow = r>>1;
    // stored offset in composite = (r&1)*64 + h*32 + q*16, XOR ((crow&7)<<4).
    const int rA0  = wrM * 64 + l31;
    const int rB0  = wcN * 64 + l31;
    const int fb   = (l31 & 1) * 64 + h * 32;
    const int aA0 = (rA0 >> 1) * 128 + ((fb)      ^ (((rA0 >> 1) & 7) << 4));
    const int aA1 = (rA0 >> 1) * 128 + ((fb + 16) ^ (((rA0 >> 1) & 7) << 4));
    const int aB0 = 16384 + (rB0 >> 1) * 128 + ((fb)      ^ (((rB0 >> 1) & 7) << 4));
    const int aB1 = 16384 + (rB0 >> 1) * 128 + ((fb + 16) ^ (((rB0 >> 1) & 7) << 4));

    f32x16 acc[2][2];
    #pragma unroll
    for (int i = 0; i < 2; ++i)
        #pragma unroll
        for (int j = 0; j < 2; ++j) acc[i][j] = (f32x16)0.f;

    #define BAR() __builtin_amdgcn_s_barrier()
    #define SCB() __builtin_amdgcn_sched_barrier(0)

    // prologue: K-tile (phase) -> buf0, (phase+1) -> buf1
    STAGE(phase, 0);
    STAGE(phase + 1, 1);
    asm volatile("s_waitcnt vmcnt(3)" ::: "memory");   // first tile landed
    SCB();
    BAR();

    for (int kt = 0; kt < 16; ++kt) {
        const int bb = (kt & 1) * 24576;
        i64x2 xq0[2], xq1[2], wq0[2], wq1[2];
        #pragma unroll
        for (int mi = 0; mi < 2; ++mi) {
            xq0[mi] = *(const i64x2*)(ldsb + bb + aA0 + mi * 2048);
            xq1[mi] = *(const i64x2*)(ldsb + bb + aA1 + mi * 2048);
        }
        #pragma unroll
        for (int ni = 0; ni < 2; ++ni) {
            wq0[ni] = *(const i64x2*)(ldsb + bb + aB0 + ni * 2048);
            wq1[ni] = *(const i64x2*)(ldsb + bb + aB1 + ni * 2048);
        }
        asm volatile("s_waitcnt lgkmcnt(4)" ::: "memory");
        SCB();
        __builtin_amdgcn_s_setprio(1);
        #pragma unroll
        for (int mi = 0; mi < 2; ++mi)
            #pragma unroll
            for (int ni = 0; ni < 2; ++ni) {
                acc[mi][ni] = __builtin_amdgcn_mfma_f32_32x32x16_fp8_fp8(
                    wq0[ni][0], xq0[mi][0], acc[mi][ni], 0, 0, 0);   // ks0
                acc[mi][ni] = __builtin_amdgcn_mfma_f32_32x32x16_fp8_fp8(
                    wq0[ni][1], xq0[mi][1], acc[mi][ni], 0, 0, 0);   // ks1
            }
        __builtin_amdgcn_s_setprio(0);
        asm volatile("s_waitcnt lgkmcnt(0)" ::: "memory");
        SCB();
        __builtin_amdgcn_s_setprio(1);
        #pragma unroll
        for (int mi = 0; mi < 2; ++mi)
            #pragma unroll
            for (int ni = 0; ni < 2; ++ni) {
                acc[mi][ni] = __builtin_amdgcn_mfma_f32_32x32x16_fp8_fp8(
                    wq1[ni][0], xq1[mi][0], acc[mi][ni], 0, 0, 0);   // ks2
                acc[mi][ni] = __builtin_amdgcn_mfma_f32_32x32x16_fp8_fp8(
                    wq1[ni][1], xq1[mi][1], acc[mi][ni], 0, 0, 0);   // ks3
            }
        __builtin_amdgcn_s_setprio(0);
        SCB();
        BAR();                                 // all waves' reads of bb drained
        if (kt < 14) {
            STAGE(kt + 2 + phase, kt & 1);
            asm volatile("s_waitcnt vmcnt(3)" ::: "memory");  // next tile landed
            SCB();
            BAR();
        } else if (kt == 14) {
            asm volatile("s_waitcnt vmcnt(0)" ::: "memory");  // last tile landed
            SCB();
            BAR();
        }
    }

    // ---- epilogue: d2 = x2 - 2*dot + w2 -> bf16, LDS-transposed coalesced store ----
    // D layout (32x32, shape-determined): col = l31 (X-row), row = (reg&3)+8*(reg>>2)
    // +4*h (W-col). per-wave 8KB: [xr:64][128B], col-byte XOR ((xr&7)<<4)
    unsigned char* wls = ldsb + w * 8192;
    const int colw = tn * 128 + wcN * 64;
    const int rowbase = tm * 256 + wrM * 64;
    float4 w2q[2][4];
    #pragma unroll
    for (int ni = 0; ni < 2; ++ni)
        #pragma unroll
        for (int q = 0; q < 4; ++q)
            w2q[ni][q] = *(const float4*)(w2 + colw + ni * 32 + q * 8 + h * 4);

    float mnA[2]; int ixA[2];
    #pragma unroll
    for (int mi = 0; mi < 2; ++mi) {
        const int xr = mi * 32 + l31;
        const float xx = x2[rowbase + xr];
        float mn = __builtin_inff(); int ix = 0x7fffffff;
        #pragma unroll
        for (int ni = 0; ni < 2; ++ni) {
            #pragma unroll
            for (int q = 0; q < 4; ++q) {
                float dv[4];
                ushort4 st;
                #pragma unroll
                for (int t = 0; t < 4; ++t) {
                    dv[t] = xx - 2.f * acc[mi][ni][q * 4 + t] + w2q[ni][q][t];
                    st[t] = (unsigned short)f32_to_bf16(dv[t]);
                }
                *(ushort4*)(wls + xr * 128
                            + ((ni * 64 + q * 16 + h * 8) ^ ((xr & 7) << 4))) = st;
                #pragma unroll
                for (int t = 0; t < 4; ++t) {
                    const int cand = colw + ni * 32 + q * 8 + h * 4 + t;
                    if (dv[t] < mn || (dv[t] == mn && cand < ix)) { mn = dv[t]; ix = cand; }
                }
            }
        }
        float om = __shfl_xor(mn, 32);
        int   oi = __shfl_xor(ix, 32);
        if (om < mn || (om == mn && oi < ix)) { mn = om; ix = oi; }
        mnA[mi] = mn; ixA[mi] = ix;
    }
    asm volatile("s_waitcnt lgkmcnt(0)" ::: "memory");  // wave-private LDS writes done
    SCB();
    // read back transposed: 8 lanes x 16B = 128B contiguous per d2 row
    #pragma unroll
    for (int j = 0; j < 8; ++j) {
        const int rl = j * 8 + (lane >> 3);      // row_local 0..63
        const int cb = (lane & 7) * 16;
        short8 v = *(const short8*)(wls + rl * 128 + (cb ^ ((rl & 7) << 4)));
        *(short8*)((char*)(d2 + (size_t)(rowbase + rl) * MN + colw) + cb) = v;
    }
    __syncthreads();
    // per-row argmin partials across the 2 N-waves
    float* smin = (float*)ldsb;            // [256][2]
    int*   sidx = (int*)(ldsb + 2048);     // [256][2]
    if (lane < 32) {
        #pragma unroll
        for (int mi = 0; mi < 2; ++mi) {
            const int rloc = wrM * 64 + mi * 32 + l31;
            smin[rloc * 2 + wcN] = mnA[mi];
            sidx[rloc * 2 + wcN] = ixA[mi];
        }
    }
    __syncthreads();
    if (tid < 256) {
        float m0 = smin[tid * 2];     int i0 = sidx[tid * 2];
        float m1 = smin[tid * 2 + 1]; int i1 = sidx[tid * 2 + 1];
        bool take1 = (m1 < m0) || (m1 == m0 && i1 < i0);
        const int row = tm * 256 + tid;
        pmin[(size_t)row * NJB + tn] = take1 ? m1 : m0;
        pidx[(size_t)row * NJB + tn] = take1 ? i1 : i0;
    }
    #undef STAGE
    #undef BAR
    #undef SCB
}

// ---------- Kernel 3: fused argmin-finish + influence-weighted row sum ----------
__global__ __launch_bounds__(256) void k_loss(
    const ushort_t* __restrict__ d2, const float* __restrict__ pmin,
    const int* __restrict__ pidx, float* __restrict__ lossb) {
    __shared__ float etab[255];
    __shared__ float red[4];
    __shared__ int bmu_s;
    int t = threadIdx.x;
    if (t < 255) etab[t] = __expf(-(float)(t * t) * 1e-4f);  // exp(-r^2/T^2), T=100
    int row = blockIdx.x;
    if (t < 64) {
        float m0 = pmin[(size_t)row * NJB + t];
        int   i0 = pidx[(size_t)row * NJB + t];
        float m1 = pmin[(size_t)row * NJB + t + 64];
        int   i1 = pidx[(size_t)row * NJB + t + 64];
        if (m1 < m0 || (m1 == m0 && i1 < i0)) { m0 = m1; i0 = i1; }
        #pragma unroll
        for (int d = 1; d < 64; d <<= 1) {
            float om = __shfl_xor(m0, d);
            int   oi = __shfl_xor(i0, d);
            if (om < m0 || (om == m0 && oi < i0)) { m0 = om; i0 = oi; }
        }
        if (t == 0) bmu_s = i0;
    }
    __syncthreads();
    int bl = bmu_s;
    int bi = bl >> 7, bj = bl & 127;
    const ushort_t* dr = d2 + (size_t)row * MN;
    float s = 0.f;
    #pragma unroll
    for (int c = 0; c < 8; ++c) {
        int j = c * 2048 + t * 8;
        short8 v = *(const short8*)&dr[j];
        int di = abs((j >> 7) - bi);
        int jc = j & 127;
        #pragma unroll
        for (int u = 0; u < 8; ++u) {
            int mh = di + abs(jc + u - bj);
            s += bf16_to_f32((ushort_t)v[u]) * etab[mh];
        }
    }
    #pragma unroll
    for (int d = 1; d < 64; d <<= 1) s += __shfl_xor(s, d);
    if ((t & 63) == 0) red[t >> 6] = s;
    __syncthreads();
    if (t == 0) lossb[row] = red[0] + red[1] + red[2] + red[3];
}

// ---------- Kernel 4: final deterministic reduce ----------
__global__ __launch_bounds__(256) void k_final(
    const float* __restrict__ lossb, float* __restrict__ out) {
    __shared__ float red[4];
    int t = threadIdx.x;
    float s = 0.f;
    #pragma unroll
    for (int k = 0; k < 16; ++k) s += lossb[t + k * 256];
    #pragma unroll
    for (int d = 1; d < 64; d <<= 1) s += __shfl_xor(s, d);
    if ((t & 63) == 0) red[t >> 6] = s;
    __syncthreads();
    if (t == 0) out[0] = (red[0] + red[1] + red[2] + red[3]) * (1.0f / 128.0f);
}

extern "C" void kernel_launch(void* const* d_in, const int* in_sizes, int n_in,
                              void* d_out, int out_size, void* d_ws, size_t ws_size,
                              hipStream_t stream) {
    const float* X = (const float*)d_in[0];
    const float* W = (const float*)d_in[1];
    unsigned char* ws = (unsigned char*)d_ws;
    unsigned char* Xf8 = ws;
    unsigned char* Wf8 = ws + 4194304;
    float*    x2   = (float*)(ws + 20971520);
    float*    w2   = (float*)(ws + 20987904);
    ushort_t* d2   = (ushort_t*)(ws + 21053440);
    float*    pmin = (float*)(ws + 155271168);
    int*      pidx = (int*)(ws + 157368320);
    float*    lossb= (float*)(ws + 159465472);

    k_convert<<<5120, 256, 0, stream>>>(X, W, Xf8, Wf8, x2, w2);
    k_gemm<<<2048, 512, 0, stream>>>(Xf8, Wf8, x2, w2, d2, pmin, pidx);
    k_loss<<<4096, 256, 0, stream>>>(d2, pmin, pidx, lossb);
    k_final<<<1, 256, 0, stream>>>(lossb, (float*)d_out);
}